// Round 5
// baseline (106.413 us; speedup 1.0000x reference)
//
#include <hip/hip_runtime.h>
#include <math.h>

#define kB 4
#define kM 4096
#define kN (kB * kM)
#define kPadF -999.0f
#define kPadI -999

// numpy-mimicking squared norm: (x*x + y*y) + z*z, all round-to-nearest,
// no fma contraction (np.sum over axis -1 of cb*cb).
__device__ __forceinline__ float sq_np(float x, float y, float z) {
    return __fadd_rn(__fadd_rn(__fmul_rn(x, x), __fmul_rn(y, y)),
                     __fmul_rn(z, z));
}

// ---------------------------------------------------------------------------
// Kernel 1: per-atom outputs — dihedral (col 0), partners (cols 2..7) —
// plus pre-gather of (x, y, z, sq) into ws for the nbr kernel.
// ---------------------------------------------------------------------------
__global__ __launch_bounds__(64)
void per_atom_kernel(const float* __restrict__ coords,   // (B,M,3)
                     const int*   __restrict__ cidx,     // (N,)
                     const int*   __restrict__ partners, // (N,2)
                     const int*   __restrict__ aidx,     // (N,4)
                     float*       __restrict__ out,      // (N,8)
                     float4*      __restrict__ ws)       // (N,) gathered
{
    int i = blockIdx.x * 64 + threadIdx.x;
    if (i >= kN) return;
    int b = i >> 12;  // atom_batch = i // M, M = 4096

    // ---- pre-gather for nbr kernel: x, y, z, sq (numpy rounding) ----
    {
        int gc = cidx[i];
        const float* s = coords + (size_t)(b * kM + gc) * 3;
        float x = s[0], y = s[1], z = s[2];
        ws[i] = make_float4(x, y, z, sq_np(x, y, z));
    }

    // ---- partners (cols 2..7) ----
    float o2, o3, o4, o5, o6, o7;
    int p0 = partners[2 * i + 0];
    int p1 = partners[2 * i + 1];
    if (p0 == kPadI) { o2 = o3 = o4 = kPadF; }
    else {
        const float* s = coords + (size_t)(b * kM + p0) * 3;
        o2 = s[0]; o3 = s[1]; o4 = s[2];
    }
    if (p1 == kPadI) { o5 = o6 = o7 = kPadF; }
    else {
        const float* s = coords + (size_t)(b * kM + p1) * 3;
        o5 = s[0]; o6 = s[1]; o7 = s[2];
    }

    // ---- dihedral (col 0) ----
    int4 a = *reinterpret_cast<const int4*>(aidx + 4 * i);
    float ang = kPadF;
    if (a.x != kPadI && a.y != kPadI && a.z != kPadI && a.w != kPadI) {
        int ai[4] = {a.x, a.y, a.z, a.w};
        float P[4][3];
        #pragma unroll
        for (int k = 0; k < 4; ++k) {
            int g  = ai[k];
            int gb = g >> 12;
            int gc = cidx[g];
            const float* s = coords + (size_t)(gb * kM + gc) * 3;
            P[k][0] = s[0]; P[k][1] = s[1]; P[k][2] = s[2];
        }
        float b1x = P[1][0] - P[0][0], b1y = P[1][1] - P[0][1], b1z = P[1][2] - P[0][2];
        float b2x = P[2][0] - P[1][0], b2y = P[2][1] - P[1][1], b2z = P[2][2] - P[1][2];
        float b3x = P[3][0] - P[2][0], b3y = P[3][1] - P[2][1], b3z = P[3][2] - P[2][2];
        float n1x = b1y * b2z - b1z * b2y;
        float n1y = b1z * b2x - b1x * b2z;
        float n1z = b1x * b2y - b1y * b2x;
        float n2x = b2y * b3z - b2z * b3y;
        float n2y = b2z * b3x - b2x * b3z;
        float n2z = b2x * b3y - b2y * b3x;
        float nb2 = sqrtf(b2x * b2x + b2y * b2y + b2z * b2z) + 1e-12f;
        float inv = 1.0f / nb2;
        float ux = b2x * inv, uy = b2y * inv, uz = b2z * inv;
        float m1x = n1y * uz - n1z * uy;
        float m1y = n1z * ux - n1x * uz;
        float m1z = n1x * uy - n1y * ux;
        float x = n1x * n2x + n1y * n2y + n1z * n2z;
        float y = m1x * n2x + m1y * n2y + m1z * n2z;
        ang = atan2f(y, x);
    }

    float4* o = reinterpret_cast<float4*>(out + (size_t)i * 8);
    o[0] = make_float4(ang, 0.0f, o2, o3);   // col 1 = 0, accumulated later
    o[1] = make_float4(o4, o5, o6, o7);
}

// ---------------------------------------------------------------------------
// Kernel 2: masked pairwise-distance row sums (col 1). BRANCHLESS.
// Grid 1024 = 16 row-blocks (1024 rows) x 64 col-chunks (64 cols).
// 4 blocks/CU, 16 waves/CU. 4 rows/thread in registers; 64 columns in LDS.
// Per pair (numpy-order rounding, no contraction on the d2 path):
//   dot  = fma(z, fma(y, mul(x)))            (gemm-style k-order)
//   d2   = (sq_i + sq_j) - (2*dot)           (all rn, no fused sub)
//   dist = sqrt(max(d2,0) + 1e-12)
//   sum += (dist <= 7) ? dist : 0            (cndmask, no branch)
// Pad columns self-exclude (dist ~ 1700); pad rows masked at the write.
// ---------------------------------------------------------------------------
__global__ __launch_bounds__(256)
void nbr_kernel(const float4* __restrict__ ws,  // (N,) x,y,z,sq
                float*        __restrict__ out) // (N,8)
{
    __shared__ float4 sc[64];

    int rowBlk = blockIdx.x >> 6;     // 0..15  (1024 rows each)
    int colChk = blockIdx.x & 63;     // 0..63  (64 cols each)
    int row0   = rowBlk << 10;
    int b      = rowBlk >> 2;         // 4 row-blocks per batch
    int col0   = colChk << 6;

    int tid = threadIdx.x;
    if (tid < 64) sc[tid] = ws[(size_t)b * kM + col0 + tid];
    __syncthreads();

    // 4 rows per thread: row0 + tid + k*256
    float rx[4], ry[4], rz[4], rsq[4], sum[4];
    bool  rv[4];
    #pragma unroll
    for (int k = 0; k < 4; ++k) {
        float4 ci = ws[row0 + tid + (k << 8)];
        rx[k] = ci.x; ry[k] = ci.y; rz[k] = ci.z; rsq[k] = ci.w;
        rv[k] = (ci.x != kPadF);
        sum[k] = 0.0f;
    }

    for (int j = 0; j < 64; j += 4) {
        float4 cc0 = sc[j + 0], cc1 = sc[j + 1], cc2 = sc[j + 2], cc3 = sc[j + 3];
        #pragma unroll
        for (int u = 0; u < 4; ++u) {
            float4 c = (u == 0) ? cc0 : (u == 1) ? cc1 : (u == 2) ? cc2 : cc3;
            #pragma unroll
            for (int k = 0; k < 4; ++k) {
                float dot  = __fmaf_rn(rz[k], c.z,
                             __fmaf_rn(ry[k], c.y, __fmul_rn(rx[k], c.x)));
                float t1   = __fadd_rn(rsq[k], c.w);
                float d2   = __fsub_rn(t1, __fmul_rn(2.0f, dot));
                float dist = sqrtf(__fadd_rn(fmaxf(d2, 0.0f), 1e-12f));
                sum[k] += (dist <= 7.0f) ? dist : 0.0f;
            }
        }
    }

    #pragma unroll
    for (int k = 0; k < 4; ++k) {
        if (rv[k] && sum[k] != 0.0f) {
            atomicAdd(out + (size_t)(row0 + tid + (k << 8)) * 8 + 1, sum[k]);
        }
    }
}

// ---------------------------------------------------------------------------
// Fallback (ws too small): self-contained nbr kernel with LDS staging.
// ---------------------------------------------------------------------------
__global__ __launch_bounds__(256)
void nbr_kernel_lds(const float* __restrict__ coords,
                    const int*   __restrict__ cidx,
                    float*       __restrict__ out)
{
    __shared__ float4 sc[kM];
    int b    = blockIdx.x >> 6;
    int row0 = (blockIdx.x & 63) << 6;
    for (int j = threadIdx.x; j < kM; j += 256) {
        int idx = cidx[b * kM + j];
        const float* s = coords + (size_t)(b * kM + idx) * 3;
        float x = s[0], y = s[1], z = s[2];
        sc[j] = make_float4(x, y, z, sq_np(x, y, z));
    }
    __syncthreads();
    int r   = row0 + (threadIdx.x >> 2);
    int sub = threadIdx.x & 3;
    float4 ci = sc[r];
    float sum = 0.0f;
    for (int jj = 0; jj < kM / 4; ++jj) {
        float4 c   = sc[4 * jj + sub];
        float dot  = __fmaf_rn(ci.z, c.z,
                     __fmaf_rn(ci.y, c.y, __fmul_rn(ci.x, c.x)));
        float t1   = __fadd_rn(ci.w, c.w);
        float d2   = __fsub_rn(t1, __fmul_rn(2.0f, dot));
        float dist = sqrtf(__fadd_rn(fmaxf(d2, 0.0f), 1e-12f));
        sum += (dist <= 7.0f) ? dist : 0.0f;
    }
    sum += __shfl_xor(sum, 1);
    sum += __shfl_xor(sum, 2);
    if (sub == 0)
        out[(size_t)(b * kM + r) * 8 + 1] = (ci.x != kPadF) ? sum : 0.0f;
}

// ---------------------------------------------------------------------------
extern "C" void kernel_launch(void* const* d_in, const int* in_sizes, int n_in,
                              void* d_out, int out_size, void* d_ws, size_t ws_size,
                              hipStream_t stream) {
    const float* coords   = (const float*)d_in[0];
    const int*   cidx     = (const int*)d_in[2];
    const int*   partners = (const int*)d_in[3];
    const int*   aidx     = (const int*)d_in[4];
    float*       out      = (float*)d_out;
    float4*      ws       = (float4*)d_ws;

    hipLaunchKernelGGL(per_atom_kernel, dim3(kN / 64), dim3(64), 0, stream,
                       coords, cidx, partners, aidx, out, ws);

    if (ws_size >= (size_t)kN * sizeof(float4)) {
        hipLaunchKernelGGL(nbr_kernel, dim3(1024), dim3(256), 0, stream,
                           ws, out);
    } else {
        hipLaunchKernelGGL(nbr_kernel_lds, dim3(kB * 64), dim3(256), 0, stream,
                           coords, cidx, out);
    }
}

// Round 6
// 81.931 us; speedup vs baseline: 1.2988x; 1.2988x over previous
//
#include <hip/hip_runtime.h>
#include <math.h>

#define kB 4
#define kM 4096
#define kN (kB * kM)
#define kPadF -999.0f
#define kPadI -999

// numpy-mimicking squared norm: (x*x + y*y) + z*z, all round-to-nearest,
// no fma contraction (np.sum over axis -1 of cb*cb).
__device__ __forceinline__ float sq_np(float x, float y, float z) {
    return __fadd_rn(__fadd_rn(__fmul_rn(x, x), __fmul_rn(y, y)),
                     __fmul_rn(z, z));
}

// raw v_sqrt_f32 (approx, <=1 ulp). The inclusion mask is decided by the
// exact d2<=49 compare, so sqrt value error only perturbs the sum ~1e-6.
__device__ __forceinline__ float fast_sqrt(float x) {
#if __has_builtin(__builtin_amdgcn_sqrtf)
    return __builtin_amdgcn_sqrtf(x);
#else
    float r;
    asm volatile("v_sqrt_f32 %0, %1" : "=v"(r) : "v"(x));
    return r;
#endif
}

// ---------------------------------------------------------------------------
// Kernel 1: per-atom outputs — dihedral (col 0), partners (cols 2..7) —
// plus pre-gather of (x, y, z, sq) into ws for the nbr kernel.
// ---------------------------------------------------------------------------
__global__ __launch_bounds__(64)
void per_atom_kernel(const float* __restrict__ coords,   // (B,M,3)
                     const int*   __restrict__ cidx,     // (N,)
                     const int*   __restrict__ partners, // (N,2)
                     const int*   __restrict__ aidx,     // (N,4)
                     float*       __restrict__ out,      // (N,8)
                     float4*      __restrict__ ws)       // (N,) gathered
{
    int i = blockIdx.x * 64 + threadIdx.x;
    if (i >= kN) return;
    int b = i >> 12;  // atom_batch = i // M, M = 4096

    // ---- pre-gather for nbr kernel: x, y, z, sq (numpy rounding) ----
    {
        int gc = cidx[i];
        const float* s = coords + (size_t)(b * kM + gc) * 3;
        float x = s[0], y = s[1], z = s[2];
        ws[i] = make_float4(x, y, z, sq_np(x, y, z));
    }

    // ---- partners (cols 2..7) ----
    float o2, o3, o4, o5, o6, o7;
    int p0 = partners[2 * i + 0];
    int p1 = partners[2 * i + 1];
    if (p0 == kPadI) { o2 = o3 = o4 = kPadF; }
    else {
        const float* s = coords + (size_t)(b * kM + p0) * 3;
        o2 = s[0]; o3 = s[1]; o4 = s[2];
    }
    if (p1 == kPadI) { o5 = o6 = o7 = kPadF; }
    else {
        const float* s = coords + (size_t)(b * kM + p1) * 3;
        o5 = s[0]; o6 = s[1]; o7 = s[2];
    }

    // ---- dihedral (col 0) ----
    int4 a = *reinterpret_cast<const int4*>(aidx + 4 * i);
    float ang = kPadF;
    if (a.x != kPadI && a.y != kPadI && a.z != kPadI && a.w != kPadI) {
        int ai[4] = {a.x, a.y, a.z, a.w};
        float P[4][3];
        #pragma unroll
        for (int k = 0; k < 4; ++k) {
            int g  = ai[k];
            int gb = g >> 12;
            int gc = cidx[g];
            const float* s = coords + (size_t)(gb * kM + gc) * 3;
            P[k][0] = s[0]; P[k][1] = s[1]; P[k][2] = s[2];
        }
        float b1x = P[1][0] - P[0][0], b1y = P[1][1] - P[0][1], b1z = P[1][2] - P[0][2];
        float b2x = P[2][0] - P[1][0], b2y = P[2][1] - P[1][1], b2z = P[2][2] - P[1][2];
        float b3x = P[3][0] - P[2][0], b3y = P[3][1] - P[2][1], b3z = P[3][2] - P[2][2];
        float n1x = b1y * b2z - b1z * b2y;
        float n1y = b1z * b2x - b1x * b2z;
        float n1z = b1x * b2y - b1y * b2x;
        float n2x = b2y * b3z - b2z * b3y;
        float n2y = b2z * b3x - b2x * b3z;
        float n2z = b2x * b3y - b2y * b3x;
        float nb2 = sqrtf(b2x * b2x + b2y * b2y + b2z * b2z) + 1e-12f;
        float inv = 1.0f / nb2;
        float ux = b2x * inv, uy = b2y * inv, uz = b2z * inv;
        float m1x = n1y * uz - n1z * uy;
        float m1y = n1z * ux - n1x * uz;
        float m1z = n1x * uy - n1y * ux;
        float x = n1x * n2x + n1y * n2y + n1z * n2z;
        float y = m1x * n2x + m1y * n2y + m1z * n2z;
        ang = atan2f(y, x);
    }

    float4* o = reinterpret_cast<float4*>(out + (size_t)i * 8);
    o[0] = make_float4(ang, 0.0f, o2, o3);   // col 1 = 0, accumulated later
    o[1] = make_float4(o4, o5, o6, o7);
}

// ---------------------------------------------------------------------------
// Kernel 2: masked pairwise-distance row sums (col 1).
// Grid 1024 = 16 row-blocks (1024 rows) x 64 col-chunks (64 cols).
// 4 blocks/CU, 16 waves/CU. 4 rows/thread in registers; 64 columns in LDS.
// Mask is EXACT without sqrt:  dist<=7  <=>  d2<=49.0f  (verified at the
// fp32 boundary for correctly-rounded sqrt; 1e-12 << ulp(49)).
// sqrt runs only under a wave-uniform __any branch (~16% of iters), using
// raw v_sqrt_f32 (value-only, <=1ulp).
// ---------------------------------------------------------------------------
__global__ __launch_bounds__(256)
void nbr_kernel(const float4* __restrict__ ws,  // (N,) x,y,z,sq
                float*        __restrict__ out) // (N,8)
{
    __shared__ float4 sc[64];

    int rowBlk = blockIdx.x >> 6;     // 0..15  (1024 rows each)
    int colChk = blockIdx.x & 63;     // 0..63  (64 cols each)
    int row0   = rowBlk << 10;
    int b      = rowBlk >> 2;         // 4 row-blocks per batch
    int col0   = colChk << 6;

    int tid = threadIdx.x;
    if (tid < 64) sc[tid] = ws[(size_t)b * kM + col0 + tid];
    __syncthreads();

    // 4 rows per thread: row0 + tid + k*256
    float rx[4], ry[4], rz[4], rsq[4], sum[4];
    bool  rv[4];
    #pragma unroll
    for (int k = 0; k < 4; ++k) {
        float4 ci = ws[row0 + tid + (k << 8)];
        rx[k] = ci.x; ry[k] = ci.y; rz[k] = ci.z; rsq[k] = ci.w;
        rv[k] = (ci.x != kPadF);
        sum[k] = 0.0f;
    }

    for (int j = 0; j < 64; j += 4) {
        float4 cc0 = sc[j + 0], cc1 = sc[j + 1], cc2 = sc[j + 2], cc3 = sc[j + 3];
        #pragma unroll
        for (int u = 0; u < 4; ++u) {
            float4 c = (u == 0) ? cc0 : (u == 1) ? cc1 : (u == 2) ? cc2 : cc3;
            #pragma unroll
            for (int k = 0; k < 4; ++k) {
                float dot = __fmaf_rn(rz[k], c.z,
                            __fmaf_rn(ry[k], c.y, __fmul_rn(rx[k], c.x)));
                float d2  = __fsub_rn(__fadd_rn(rsq[k], c.w),
                                      __fmul_rn(2.0f, dot));
                bool  in  = (d2 <= 49.0f);
                if (__any(in)) {   // wave-uniform scalar branch, ~16% taken
                    float d2m  = __fadd_rn(fmaxf(d2, 0.0f), 1e-12f);
                    float dist = fast_sqrt(d2m);
                    sum[k] += in ? dist : 0.0f;
                }
            }
        }
    }

    #pragma unroll
    for (int k = 0; k < 4; ++k) {
        if (rv[k] && sum[k] != 0.0f) {
            atomicAdd(out + (size_t)(row0 + tid + (k << 8)) * 8 + 1, sum[k]);
        }
    }
}

// ---------------------------------------------------------------------------
// Fallback (ws too small): self-contained nbr kernel with LDS staging.
// ---------------------------------------------------------------------------
__global__ __launch_bounds__(256)
void nbr_kernel_lds(const float* __restrict__ coords,
                    const int*   __restrict__ cidx,
                    float*       __restrict__ out)
{
    __shared__ float4 sc[kM];
    int b    = blockIdx.x >> 6;
    int row0 = (blockIdx.x & 63) << 6;
    for (int j = threadIdx.x; j < kM; j += 256) {
        int idx = cidx[b * kM + j];
        const float* s = coords + (size_t)(b * kM + idx) * 3;
        float x = s[0], y = s[1], z = s[2];
        sc[j] = make_float4(x, y, z, sq_np(x, y, z));
    }
    __syncthreads();
    int r   = row0 + (threadIdx.x >> 2);
    int sub = threadIdx.x & 3;
    float4 ci = sc[r];
    float sum = 0.0f;
    for (int jj = 0; jj < kM / 4; ++jj) {
        float4 c   = sc[4 * jj + sub];
        float dot  = __fmaf_rn(ci.z, c.z,
                     __fmaf_rn(ci.y, c.y, __fmul_rn(ci.x, c.x)));
        float d2   = __fsub_rn(__fadd_rn(ci.w, c.w), __fmul_rn(2.0f, dot));
        bool  in   = (d2 <= 49.0f);
        if (__any(in)) {
            float d2m  = __fadd_rn(fmaxf(d2, 0.0f), 1e-12f);
            float dist = fast_sqrt(d2m);
            sum += in ? dist : 0.0f;
        }
    }
    sum += __shfl_xor(sum, 1);
    sum += __shfl_xor(sum, 2);
    if (sub == 0)
        out[(size_t)(b * kM + r) * 8 + 1] = (ci.x != kPadF) ? sum : 0.0f;
}

// ---------------------------------------------------------------------------
extern "C" void kernel_launch(void* const* d_in, const int* in_sizes, int n_in,
                              void* d_out, int out_size, void* d_ws, size_t ws_size,
                              hipStream_t stream) {
    const float* coords   = (const float*)d_in[0];
    const int*   cidx     = (const int*)d_in[2];
    const int*   partners = (const int*)d_in[3];
    const int*   aidx     = (const int*)d_in[4];
    float*       out      = (float*)d_out;
    float4*      ws       = (float4*)d_ws;

    hipLaunchKernelGGL(per_atom_kernel, dim3(kN / 64), dim3(64), 0, stream,
                       coords, cidx, partners, aidx, out, ws);

    if (ws_size >= (size_t)kN * sizeof(float4)) {
        hipLaunchKernelGGL(nbr_kernel, dim3(1024), dim3(256), 0, stream,
                           ws, out);
    } else {
        hipLaunchKernelGGL(nbr_kernel_lds, dim3(kB * 64), dim3(256), 0, stream,
                           coords, cidx, out);
    }
}